// Round 1
// baseline (20273.317 us; speedup 1.0000x reference)
//
#include <hip/hip_runtime.h>
#include <math.h>

#define LNUM 4
#define DM 768
#define DI 1536
#define DS_N 16
#define DR 48
#define KCV 4
#define VV 32000
#define BB 2
#define SEQ 2048
#define MT (BB*SEQ)     // 4096 tokens
#define XPD 80          // DR + 2*DS

static __device__ __forceinline__ float siluf(float x){ return x/(1.f+expf(-x)); }

// ---------------- embedding (optionally sequence-flipped ids) ----------------
__global__ void embed_k(const int* __restrict__ ids, const float* __restrict__ emb,
                        float* __restrict__ h, int flip){
  size_t i = (size_t)blockIdx.x*blockDim.x + threadIdx.x;
  size_t n = (size_t)MT*(DM/4);
  if(i>=n) return;
  int t = (int)(i/(DM/4)); int d4 = (int)(i%(DM/4));
  int b = t/SEQ, s = t%SEQ;
  int tok = flip ? ids[b*SEQ + (SEQ-1-s)] : ids[t];
  const float4* src = (const float4*)(emb + (size_t)tok*DM);
  float4* dst = (float4*)(h + (size_t)t*DM);
  dst[d4] = src[d4];
}

// ---------------- RMSNorm; supports writing into a wider output (combined) ---
// out[t, ooff + i] (row stride ldo) = rms(x[ti,:]) ; ti = flip? mirrored row
__global__ void rmsnorm_k(const float* __restrict__ x, const float* __restrict__ w,
                          float* __restrict__ o, int dim, int ldo, int ooff, int flip){
  int t = blockIdx.x;
  int b = t/SEQ, s = t%SEQ;
  int ti = flip ? (b*SEQ + (SEQ-1-s)) : t;
  const float* xr = x + (size_t)ti*dim;
  float ss = 0.f;
  for(int i=threadIdx.x;i<dim;i+=blockDim.x){ float v=xr[i]; ss += v*v; }
  for(int off=32;off>0;off>>=1) ss += __shfl_down(ss,off,64);
  __shared__ float red[8];
  int wid = threadIdx.x>>6, lane = threadIdx.x&63;
  if(lane==0) red[wid]=ss;
  __syncthreads();
  if(threadIdx.x==0){
    float tot=0.f; int nw = blockDim.x>>6;
    for(int i=0;i<nw;i++) tot += red[i];
    red[0] = rsqrtf(tot/(float)dim + 1e-5f);
  }
  __syncthreads();
  float sc = red[0];
  float* orow = o + (size_t)t*ldo + ooff;
  for(int i=threadIdx.x;i<dim;i+=blockDim.x) orow[i] = xr[i]*sc*w[i];
}

// ---------------- fp32 tiled GEMM:  C[m,n] = (ADD?C:0) + sum_k A[m,k]*W[n,k] --
// A: (Mm,Kk) row-major with row stride lda; W: (Nn,Kk) row-major (stride Kk).
// 128x128 tile, BK=8, 256 threads, 8x8 per thread. Kk must be multiple of 8.
template<bool ADD>
__global__ __launch_bounds__(256) void gemm_nt(const float* __restrict__ A, int lda,
                        const float* __restrict__ W, float* __restrict__ C,
                        int Mm, int Nn, int Kk){
  __shared__ float As[8][132];
  __shared__ float Bs[8][132];
  int tid = threadIdx.x;
  int tx = tid & 15, ty = tid >> 4;
  int bm = blockIdx.y*128, bn = blockIdx.x*128;
  float acc[8][8];
  #pragma unroll
  for(int i=0;i<8;i++)
    #pragma unroll
    for(int j=0;j<8;j++) acc[i][j]=0.f;

  int lr = tid>>1;           // 0..127 (tile row)
  int kq = (tid&1)*4;        // 0 or 4
  for(int k0=0;k0<Kk;k0+=8){
    float4 va = make_float4(0,0,0,0), vb = make_float4(0,0,0,0);
    int gm = bm+lr, gn = bn+lr;
    if(gm<Mm) va = *(const float4*)(A + (size_t)gm*lda + k0 + kq);
    if(gn<Nn) vb = *(const float4*)(W + (size_t)gn*Kk  + k0 + kq);
    As[kq+0][lr]=va.x; As[kq+1][lr]=va.y; As[kq+2][lr]=va.z; As[kq+3][lr]=va.w;
    Bs[kq+0][lr]=vb.x; Bs[kq+1][lr]=vb.y; Bs[kq+2][lr]=vb.z; Bs[kq+3][lr]=vb.w;
    __syncthreads();
    #pragma unroll
    for(int kk=0;kk<8;kk++){
      float a[8], bv[8];
      #pragma unroll
      for(int i=0;i<8;i++) a[i]  = As[kk][ty*8+i];
      #pragma unroll
      for(int j=0;j<8;j++) bv[j] = Bs[kk][tx*8+j];
      #pragma unroll
      for(int i=0;i<8;i++)
        #pragma unroll
        for(int j=0;j<8;j++) acc[i][j] += a[i]*bv[j];
    }
    __syncthreads();
  }
  #pragma unroll
  for(int i=0;i<8;i++){
    int gm = bm + ty*8 + i; if(gm>=Mm) continue;
    #pragma unroll
    for(int j=0;j<8;j++){
      int gn = bn + tx*8 + j; if(gn>=Nn) continue;
      size_t o = (size_t)gm*Nn + gn;
      C[o] = (ADD ? C[o] : 0.f) + acc[i][j];
    }
  }
}

// ---------------- causal depthwise conv (K=4) + SiLU ------------------------
// xz: (MT, 2*DI); xi = xz[:, :DI]. xc[t,d] = silu(sum_k xi[t-3+k,d]*cw[d,k]+cb[d])
__global__ void conv_silu_k(const float* __restrict__ xz, const float* __restrict__ cw,
                            const float* __restrict__ cb, float* __restrict__ xc){
  size_t i = (size_t)blockIdx.x*blockDim.x + threadIdx.x;
  if(i>=(size_t)MT*DI) return;
  long t = (long)(i/DI); int d = (int)(i%DI); int s = (int)(t%SEQ);
  float acc = cb[d];
  #pragma unroll
  for(int k=0;k<KCV;k++){
    int sp = s + k - (KCV-1);
    if(sp>=0){
      long tt = t + (k - (KCV-1));
      acc += xz[(size_t)tt*(2*DI) + d]*cw[d*KCV + k];
    }
  }
  xc[i] = siluf(acc);
}

// ---------------- dt = softplus(dtpre + dtb) (in place) ---------------------
__global__ void softplus_k(float* __restrict__ dtv, const float* __restrict__ dtb){
  size_t i = (size_t)blockIdx.x*blockDim.x + threadIdx.x;
  if(i>=(size_t)MT*DI) return;
  int d = (int)(i%DI);
  float x = dtv[i] + dtb[d];
  dtv[i] = (x>20.f) ? x : log1pf(expf(x));
}

// ---------------- selective-scan. One wave handles 4 d-channels x 16 states --
__global__ void scan_k(const float* __restrict__ dt, const float* __restrict__ xc,
                       const float* __restrict__ dbc, const float* __restrict__ Alog,
                       const float* __restrict__ Dp, float* __restrict__ y){
  int lane = threadIdx.x;     // 64
  int ln = lane & 15;         // state index n
  int ld = lane >> 4;         // which of 4 channels
  int d = blockIdx.x*4 + ld;
  int b = blockIdx.y;
  float Acoef = -expf(Alog[d*DS_N + ln]);
  float Dv = Dp[d];
  float h = 0.f;
  size_t tbase = (size_t)b*SEQ;
  #pragma unroll 2
  for(int s=0;s<SEQ;s++){
    size_t t = tbase + s;
    float dtv = dt[t*DI + d];
    float xv  = xc[t*DI + d];
    float Bv  = dbc[t*XPD + DR + ln];
    float Cv  = dbc[t*XPD + DR + DS_N + ln];
    float e = expf(dtv*Acoef);
    h = e*h + (dtv*xv)*Bv;
    float c = h*Cv;
    c += __shfl_xor(c, 8, 16);
    c += __shfl_xor(c, 4, 16);
    c += __shfl_xor(c, 2, 16);
    c += __shfl_xor(c, 1, 16);
    if(ln==0) y[t*DI + d] = c + Dv*xv;
  }
}

// ---------------- y *= silu(z);  z = xz[:, DI:] ------------------------------
__global__ void gate_k(float* __restrict__ y, const float* __restrict__ xz){
  size_t i = (size_t)blockIdx.x*blockDim.x + threadIdx.x;
  if(i>=(size_t)MT*DI) return;
  size_t t = i/DI; int d = (int)(i%DI);
  float z = xz[t*(2*DI) + DI + d];
  y[i] *= siluf(z);
}

// ---------------- loss -------------------------------------------------------
__global__ void zero_k(float* a){ a[0]=0.f; a[1]=0.f; }

__global__ void loss_k(const float* __restrict__ logits, const int* __restrict__ labels,
                       float* __restrict__ accum){
  int t = blockIdx.x;
  const float* row = logits + (size_t)t*VV;
  float m = -1e30f, ssum = 0.f;
  for(int i=threadIdx.x;i<VV;i+=256){
    float x = row[i];
    if(x>m){ ssum = ssum*expf(m-x) + 1.f; m = x; }
    else    ssum += expf(x-m);
  }
  __shared__ float sm[256], sv[256];
  sm[threadIdx.x]=m; sv[threadIdx.x]=ssum;
  __syncthreads();
  for(int off=128;off;off>>=1){
    if(threadIdx.x<off){
      float m1=sm[threadIdx.x], m2=sm[threadIdx.x+off];
      float s1=sv[threadIdx.x], s2=sv[threadIdx.x+off];
      float M = fmaxf(m1,m2);
      sm[threadIdx.x]=M;
      sv[threadIdx.x]=s1*expf(m1-M)+s2*expf(m2-M);
    }
    __syncthreads();
  }
  if(threadIdx.x==0){
    int lab = labels[t];
    if(lab != -100){
      float logZ = sm[0] + logf(sv[0]);
      float nll = logZ - row[lab];
      atomicAdd(&accum[0], nll);
      atomicAdd(&accum[1], 1.f);
    }
  }
}

__global__ void final_k(const float* __restrict__ accum, float* __restrict__ out){
  out[0] = accum[0]/fmaxf(accum[1],1.f);
}

// ---------------- host -------------------------------------------------------
extern "C" void kernel_launch(void* const* d_in, const int* in_sizes, int n_in,
                              void* d_out, int out_size, void* d_ws, size_t ws_size,
                              hipStream_t stream){
  (void)in_sizes; (void)n_in; (void)out_size; (void)ws_size;
  const int* ids    = (const int*)d_in[0];
  const int* labels = (const int*)d_in[1];
  const float* lm_w = (const float*)d_in[26];
  float* ws = (float*)d_ws;
  float* logits = (float*)d_out;

  size_t off=0;
  float* hbuf0 = ws+off; off += (size_t)MT*DM;
  float* hbuf1 = ws+off; off += (size_t)MT*DM;
  float* xbuf  = ws+off; off += (size_t)MT*DM;
  float* xz    = ws+off; off += (size_t)MT*2*DI;
  float* xc    = ws+off; off += (size_t)MT*DI;
  float* dbc   = ws+off; off += (size_t)MT*XPD;
  float* dtv   = ws+off; off += (size_t)MT*DI;
  float* ybuf  = ws+off; off += (size_t)MT*DI;
  float* comb  = ws+off; off += (size_t)MT*2*DM;
  float* accum = ws+off; off += 2;

  const int PW_BLOCKS = (int)(((size_t)MT*DI + 255)/256);

  for(int dir=0; dir<2; dir++){
    const float* emb   = (const float*)d_in[2+12*dir+0];
    const float* normw = (const float*)d_in[2+12*dir+1];
    const float* inw   = (const float*)d_in[2+12*dir+2];
    const float* convw = (const float*)d_in[2+12*dir+3];
    const float* convb = (const float*)d_in[2+12*dir+4];
    const float* xpw   = (const float*)d_in[2+12*dir+5];
    const float* dtw   = (const float*)d_in[2+12*dir+6];
    const float* dtbp  = (const float*)d_in[2+12*dir+7];
    const float* Alog  = (const float*)d_in[2+12*dir+8];
    const float* Dp    = (const float*)d_in[2+12*dir+9];
    const float* outw  = (const float*)d_in[2+12*dir+10];
    const float* fnorm = (const float*)d_in[2+12*dir+11];
    float* h = dir ? hbuf1 : hbuf0;

    embed_k<<<(MT*(DM/4)+255)/256,256,0,stream>>>(ids, emb, h, dir);

    for(int l=0;l<LNUM;l++){
      rmsnorm_k<<<MT,256,0,stream>>>(h, normw+l*DM, xbuf, DM, DM, 0, 0);
      { dim3 g((2*DI+127)/128,(MT+127)/128);
        gemm_nt<false><<<g,256,0,stream>>>(xbuf, DM, inw+(size_t)l*2*DI*DM, xz, MT, 2*DI, DM); }
      conv_silu_k<<<PW_BLOCKS,256,0,stream>>>(xz, convw+l*DI*KCV, convb+l*DI, xc);
      { dim3 g((XPD+127)/128,(MT+127)/128);
        gemm_nt<false><<<g,256,0,stream>>>(xc, DI, xpw+(size_t)l*XPD*DI, dbc, MT, XPD, DI); }
      { dim3 g((DI+127)/128,(MT+127)/128);
        gemm_nt<false><<<g,256,0,stream>>>(dbc, XPD, dtw+(size_t)l*DI*DR, dtv, MT, DI, DR); }
      softplus_k<<<PW_BLOCKS,256,0,stream>>>(dtv, dtbp+l*DI);
      { dim3 g(DI/4, BB);
        scan_k<<<g,64,0,stream>>>(dtv, xc, dbc, Alog+(size_t)l*DI*DS_N, Dp+l*DI, ybuf); }
      gate_k<<<PW_BLOCKS,256,0,stream>>>(ybuf, xz);
      { dim3 g((DM+127)/128,(MT+127)/128);
        gemm_nt<true><<<g,256,0,stream>>>(ybuf, DI, outw+(size_t)l*DM*DI, h, MT, DM, DI); }
    }
    // final rms -> combined; bw half is sequence-flipped back
    rmsnorm_k<<<MT,256,0,stream>>>(h, fnorm, comb, DM, 2*DM, dir?DM:0, dir);
  }

  { dim3 g((VV+127)/128,(MT+127)/128);
    gemm_nt<false><<<g,256,0,stream>>>(comb, 2*DM, lm_w, logits, MT, VV, 2*DM); }

  zero_k<<<1,1,0,stream>>>(accum);
  loss_k<<<MT,256,0,stream>>>(logits, labels, accum);
  final_k<<<1,1,0,stream>>>(accum, logits + (size_t)MT*VV);
}